// Round 2
// baseline (79334.753 us; speedup 1.0000x reference)
//
#include <hip/hip_runtime.h>
#include <math.h>

#define T_SEQ 512
#define BATCH 256
#define HID   512
#define IN0   64
#define K0    (IN0 + HID)    /* 576  */
#define K1    (HID + HID)    /* 1024 */
#define NWG   256
#define NTHR  256

// ---------------- math helpers ----------------
__device__ __forceinline__ float sigm(float x)   { return 1.0f / (1.0f + __expf(-x)); }
__device__ __forceinline__ float tanh_f(float x) { return 2.0f / (1.0f + __expf(-2.0f * x)) - 1.0f; }

// ---------------- prep: x[B][T][I] -> xT[T][I][B] ----------------
__global__ void k_transpose_x(const float* __restrict__ x, float* __restrict__ xT) {
  int idx = blockIdx.x * blockDim.x + threadIdx.x;   // over T*64*64 float4 quads
  int b4 = (idx & 63) << 2;
  int i  = (idx >> 6) & 63;
  int t  = idx >> 12;
  float4 v;
  v.x = x[(size_t)(b4 + 0) * T_SEQ * IN0 + (size_t)t * IN0 + i];
  v.y = x[(size_t)(b4 + 1) * T_SEQ * IN0 + (size_t)t * IN0 + i];
  v.z = x[(size_t)(b4 + 2) * T_SEQ * IN0 + (size_t)t * IN0 + i];
  v.w = x[(size_t)(b4 + 3) * T_SEQ * IN0 + (size_t)t * IN0 + i];
  reinterpret_cast<float4*>(xT)[idx] = v;
}

// ---------------- prep: pack W into [pair p][k][8] ----------------
// r = hc*4 + gate; gate order i,f,g,o; hcols of pair p are {2p, 2p+1}
// k < Kin  -> W_ih[row][k];  k >= Kin -> W_hh[row][k-Kin];  row = gate*512 + 2p + hc
__global__ void k_pack_w(const float* __restrict__ Wih, const float* __restrict__ Whh,
                         const float* __restrict__ bih, const float* __restrict__ bhh,
                         float* __restrict__ Wp, float* __restrict__ bp, int Kin) {
  int K = Kin + HID;
  long total = 256L * K * 8;
  long idx = (long)blockIdx.x * 256 + threadIdx.x;
  if (idx < total) {
    int r = (int)(idx & 7);
    long kk = idx >> 3;
    int k = (int)(kk % K);
    int p = (int)(kk / K);
    int gate = r & 3, hc = r >> 2;
    int row = gate * HID + 2 * p + hc;
    float v = (k < Kin) ? Wih[(long)row * Kin + k] : Whh[(long)row * HID + (k - Kin)];
    Wp[idx] = v;
  }
  if (idx < 256 * 8) {
    int r = (int)(idx & 7); int p = (int)(idx >> 3);
    int gate = r & 3, hc = r >> 2;
    int row = gate * HID + 2 * p + hc;
    bp[idx] = bih[row] + bhh[row];
  }
}

// ---------------- device-scope grid barrier ----------------
__device__ __forceinline__ void grid_barrier(unsigned* cnt, unsigned* gen) {
  __syncthreads();
  if (threadIdx.x == 0) {
    __threadfence();  // release all prior stores (device scope)
    unsigned g = __hip_atomic_load(gen, __ATOMIC_RELAXED, __HIP_MEMORY_SCOPE_AGENT);
    unsigned arrived = __hip_atomic_fetch_add(cnt, 1u, __ATOMIC_ACQ_REL, __HIP_MEMORY_SCOPE_AGENT);
    if (arrived == NWG - 1) {
      __hip_atomic_store(cnt, 0u, __ATOMIC_RELAXED, __HIP_MEMORY_SCOPE_AGENT);
      __hip_atomic_fetch_add(gen, 1u, __ATOMIC_RELEASE, __HIP_MEMORY_SCOPE_AGENT);
    } else {
      while (__hip_atomic_load(gen, __ATOMIC_ACQUIRE, __HIP_MEMORY_SCOPE_AGENT) == g) {
        __builtin_amdgcn_s_sleep(2);
      }
    }
    __threadfence();  // acquire side
  }
  __syncthreads();
}

// ---------------- GEMV inner: 1 coalesced A load + 8 wave-uniform w (SGPR) per k ----------------
template<int K>
__device__ __forceinline__ void dot_acc(const float* __restrict__ A,
                                        const float4* __restrict__ W,
                                        float4& aA, float4& aB) {
  constexpr int U = 8;
  float cur[U], nxt[U];
  #pragma unroll
  for (int j = 0; j < U; ++j) nxt[j] = 0.f;
  #pragma unroll
  for (int j = 0; j < U; ++j) cur[j] = A[j * BATCH];
  #pragma unroll 1
  for (int kb = 0; kb < K; kb += U) {
    if (kb + U < K) {
      #pragma unroll
      for (int j = 0; j < U; ++j) nxt[j] = A[(kb + U + j) * BATCH];
    }
    #pragma unroll
    for (int j = 0; j < U; ++j) {
      float4 wA = W[2 * (kb + j)];
      float4 wB = W[2 * (kb + j) + 1];
      float a = cur[j];
      aA.x = fmaf(wA.x, a, aA.x);
      aA.y = fmaf(wA.y, a, aA.y);
      aA.z = fmaf(wA.z, a, aA.z);
      aA.w = fmaf(wA.w, a, aA.w);
      aB.x = fmaf(wB.x, a, aB.x);
      aB.y = fmaf(wB.y, a, aB.y);
      aB.z = fmaf(wB.z, a, aB.z);
      aB.w = fmaf(wB.w, a, aB.w);
    }
    #pragma unroll
    for (int j = 0; j < U; ++j) cur[j] = nxt[j];
  }
}

// ---------------- persistent LSTM kernel ----------------
// grid 256 x 256. wg = (bt = wg&3 -> batch 64-slice, cg = wg>>2).
// wave wv (0..3): hidden-col pair p = cg*4+wv, lanes = 64 batch rows.
// Each wave owns pair p for BOTH layers; cell state c stays in registers.
// Pipelined: iter n does L0 step n and L1 step n-1; ONE grid sync per iter.
__global__ __launch_bounds__(NTHR, 1) void k_lstm(
    const float* __restrict__ xT,
    const float* __restrict__ Wp0, const float* __restrict__ Wp1,
    const float* __restrict__ bp0, const float* __restrict__ bp1,
    const float* __restrict__ fcw, const float* __restrict__ fcb,
    float* __restrict__ h0T,   // [2][512][256]
    float* __restrict__ h1T,   // [2][512][256]
    float* __restrict__ out,   // [256]
    unsigned* __restrict__ bar)
{
  const int tid  = threadIdx.x;
  const int lane = tid & 63;
  const int wv   = __builtin_amdgcn_readfirstlane(tid >> 6); // force SGPR -> scalar w loads
  const int wg   = blockIdx.x;
  const int bt   = wg & 3;
  const int cg   = wg >> 2;
  const int b    = bt * 64 + lane;
  const int p    = cg * 4 + wv;          // 0..255

  // zero both parities of both h states
  {
    float4* z0 = reinterpret_cast<float4*>(h0T);
    float4* z1 = reinterpret_cast<float4*>(h1T);
    const int n4 = 2 * HID * BATCH / 4;
    for (int idx = wg * NTHR + tid; idx < n4; idx += NWG * NTHR) {
      z0[idx] = make_float4(0.f, 0.f, 0.f, 0.f);
      z1[idx] = make_float4(0.f, 0.f, 0.f, 0.f);
    }
  }
  grid_barrier(bar, bar + 1);

  const float4* w0 = reinterpret_cast<const float4*>(Wp0 + (size_t)p * K0 * 8);
  const float4* w1 = reinterpret_cast<const float4*>(Wp1 + (size_t)p * K1 * 8);
  const float4 bias0A = reinterpret_cast<const float4*>(bp0)[2 * p + 0];
  const float4 bias0B = reinterpret_cast<const float4*>(bp0)[2 * p + 1];
  const float4 bias1A = reinterpret_cast<const float4*>(bp1)[2 * p + 0];
  const float4 bias1B = reinterpret_cast<const float4*>(bp1)[2 * p + 1];

  float c00 = 0.f, c01 = 0.f, c10 = 0.f, c11 = 0.f;

  for (int n = 0; n <= T_SEQ; ++n) {
    // ---- layer 0, step n: reads h0[n-1] (parity (n+1)&1), writes h0[n] (parity n&1)
    if (n < T_SEQ) {
      float4 aA = bias0A, aB = bias0B;
      dot_acc<IN0>(xT + (size_t)n * IN0 * BATCH + b, w0, aA, aB);
      dot_acc<HID>(h0T + (size_t)((n + 1) & 1) * (HID * BATCH) + b, w0 + 2 * IN0, aA, aB);
      float i0 = sigm(aA.x), f0 = sigm(aA.y), g0 = tanh_f(aA.z), o0 = sigm(aA.w);
      c00 = fmaf(f0, c00, i0 * g0);
      float hv0 = o0 * tanh_f(c00);
      float i1 = sigm(aB.x), f1 = sigm(aB.y), g1 = tanh_f(aB.z), o1 = sigm(aB.w);
      c01 = fmaf(f1, c01, i1 * g1);
      float hv1 = o1 * tanh_f(c01);
      float* dst = h0T + (size_t)(n & 1) * (HID * BATCH) + (size_t)(2 * p) * BATCH + b;
      dst[0]     = hv0;
      dst[BATCH] = hv1;
    }
    // ---- layer 1, step m=n-1: reads h0[m] (parity (n+1)&1) and h1[m-1] (parity n&1),
    //      writes h1[m] (parity (n+1)&1)
    if (n >= 1) {
      float4 aA = bias1A, aB = bias1B;
      dot_acc<HID>(h0T + (size_t)((n + 1) & 1) * (HID * BATCH) + b, w1, aA, aB);
      dot_acc<HID>(h1T + (size_t)(n & 1) * (HID * BATCH) + b, w1 + 2 * HID, aA, aB);
      float i0 = sigm(aA.x), f0 = sigm(aA.y), g0 = tanh_f(aA.z), o0 = sigm(aA.w);
      c10 = fmaf(f0, c10, i0 * g0);
      float hv0 = o0 * tanh_f(c10);
      float i1 = sigm(aB.x), f1 = sigm(aB.y), g1 = tanh_f(aB.z), o1 = sigm(aB.w);
      c11 = fmaf(f1, c11, i1 * g1);
      float hv1 = o1 * tanh_f(c11);
      float* dst = h1T + (size_t)((n + 1) & 1) * (HID * BATCH) + (size_t)(2 * p) * BATCH + b;
      dst[0]     = hv0;
      dst[BATCH] = hv1;
    }
    grid_barrier(bar, bar + 1);
  }

  // ---- final FC on h1[T-1] (parity (T-1)&1 = 1), one wg, coalesced over batch
  if (wg == 0) {
    const float* hf = h1T + (size_t)((T_SEQ - 1) & 1) * (HID * BATCH);
    float acc = 0.f;
    #pragma unroll 8
    for (int k = 0; k < HID; ++k) acc = fmaf(hf[k * BATCH + tid], fcw[k], acc);
    out[tid] = acc + fcb[0];
  }
}

// ---------------- host ----------------
extern "C" void kernel_launch(void* const* d_in, const int* in_sizes, int n_in,
                              void* d_out, int out_size, void* d_ws, size_t ws_size,
                              hipStream_t stream) {
  const float* x    = (const float*)d_in[0];
  const float* Wih0 = (const float*)d_in[1];
  const float* Whh0 = (const float*)d_in[2];
  const float* bih0 = (const float*)d_in[3];
  const float* bhh0 = (const float*)d_in[4];
  const float* Wih1 = (const float*)d_in[5];
  const float* Whh1 = (const float*)d_in[6];
  const float* bih1 = (const float*)d_in[7];
  const float* bhh1 = (const float*)d_in[8];
  const float* fcw  = (const float*)d_in[9];
  const float* fcb  = (const float*)d_in[10];

  char* ws = (char*)d_ws;
  size_t off = 0;
  auto alloc = [&](size_t bytes) -> char* {
    char* pp = ws + off;
    off = (off + bytes + 1023) & ~(size_t)1023;
    return pp;
  };
  unsigned* bar = (unsigned*)alloc(256);
  float* xT  = (float*)alloc((size_t)T_SEQ * IN0 * BATCH * 4);   // 33.5 MB
  float* Wp0 = (float*)alloc((size_t)256 * K0 * 8 * 4);          // 4.7 MB
  float* Wp1 = (float*)alloc((size_t)256 * K1 * 8 * 4);          // 8.4 MB
  float* bp0 = (float*)alloc((size_t)256 * 8 * 4);
  float* bp1 = (float*)alloc((size_t)256 * 8 * 4);
  float* h0T = (float*)alloc((size_t)2 * HID * BATCH * 4);       // 1 MB
  float* h1T = (float*)alloc((size_t)2 * HID * BATCH * 4);       // 1 MB

  (void)hipMemsetAsync(bar, 0, 256, stream);
  k_transpose_x<<<(T_SEQ * 64 * 64) / 256, 256, 0, stream>>>(x, xT);
  k_pack_w<<<(256 * K0 * 8 + 255) / 256, 256, 0, stream>>>(Wih0, Whh0, bih0, bhh0, Wp0, bp0, IN0);
  k_pack_w<<<(256 * K1 * 8 + 255) / 256, 256, 0, stream>>>(Wih1, Whh1, bih1, bhh1, Wp1, bp1, HID);
  k_lstm<<<NWG, NTHR, 0, stream>>>(xT, Wp0, Wp1, bp0, bp1, fcw, fcb, h0T, h1T, (float*)d_out, bar);
}

// Round 3
// 69928.925 us; speedup vs baseline: 1.1345x; 1.1345x over previous
//
#include <hip/hip_runtime.h>
#include <math.h>

#define T_SEQ 512
#define BATCH 256
#define HID   512
#define IN0   64
#define K1    1024           /* L1: 512 h0 + 512 h1 */
#define K0    576            /* L0: 64 x + 512 h0   */
#define NWG   256
#define NTHR  256

typedef __bf16 b16x8 __attribute__((ext_vector_type(8)));
typedef float  f32x4 __attribute__((ext_vector_type(4)));

__device__ __forceinline__ float sigm(float x)   { return 1.0f / (1.0f + __expf(-x)); }
__device__ __forceinline__ float tanh_f(float x) { return 2.0f / (1.0f + __expf(-2.0f * x)) - 1.0f; }

__device__ __forceinline__ f32x4 mfma16(b16x8 a, b16x8 b, f32x4 c) {
  return __builtin_amdgcn_mfma_f32_16x16x32_bf16(a, b, c, 0, 0, 0);
}

// ---------- prep: split W (rows permuted r = hcol*4+gate, k-concat ih|hh) ----------
__global__ void k_split_w(const float* __restrict__ Wih, const float* __restrict__ Whh,
                          const float* __restrict__ bih, const float* __restrict__ bhh,
                          __bf16* __restrict__ whi, __bf16* __restrict__ wlo,
                          float* __restrict__ bias, int Kin) {
  int K = Kin + HID;
  long idx = (long)blockIdx.x * 256 + threadIdx.x;
  long total = 2048L * K;
  if (idx < total) {
    int k = (int)(idx % K);
    int r = (int)(idx / K);
    int gate = r & 3, hcol = r >> 2;
    int row = gate * HID + hcol;
    float v = (k < Kin) ? Wih[(long)row * Kin + k] : Whh[(long)row * HID + (k - Kin)];
    __bf16 h = (__bf16)v;
    whi[idx] = h;
    wlo[idx] = (__bf16)(v - (float)h);
  }
  if (idx < 2048) {
    int r = (int)idx;
    int gate = r & 3, hcol = r >> 2;
    int row = gate * HID + hcol;
    bias[r] = bih[row] + bhh[row];
  }
}

// ---------- prep: x[B][T][I] -> split bf16 [T][B][I] ----------
__global__ void k_split_x(const float* __restrict__ x,
                          __bf16* __restrict__ xhi, __bf16* __restrict__ xlo) {
  int idx = blockIdx.x * 256 + threadIdx.x;   // dst index, [t][b][i]
  int i = idx & 63;
  int b = (idx >> 6) & 255;
  int t = idx >> 14;
  float v = x[((size_t)b * T_SEQ + t) * IN0 + i];
  __bf16 h = (__bf16)v;
  xhi[idx] = h;
  xlo[idx] = (__bf16)(v - (float)h);
}

// ---------- device-scope grid barrier (proven in round 2) ----------
__device__ __forceinline__ void grid_barrier(unsigned* cnt, unsigned* gen) {
  __syncthreads();
  if (threadIdx.x == 0) {
    __threadfence();
    unsigned g = __hip_atomic_load(gen, __ATOMIC_RELAXED, __HIP_MEMORY_SCOPE_AGENT);
    unsigned arrived = __hip_atomic_fetch_add(cnt, 1u, __ATOMIC_ACQ_REL, __HIP_MEMORY_SCOPE_AGENT);
    if (arrived == NWG - 1) {
      __hip_atomic_store(cnt, 0u, __ATOMIC_RELAXED, __HIP_MEMORY_SCOPE_AGENT);
      __hip_atomic_fetch_add(gen, 1u, __ATOMIC_RELEASE, __HIP_MEMORY_SCOPE_AGENT);
    } else {
      while (__hip_atomic_load(gen, __ATOMIC_ACQUIRE, __HIP_MEMORY_SCOPE_AGENT) == g) {
        __builtin_amdgcn_s_sleep(2);
      }
    }
    __threadfence();
  }
  __syncthreads();
}

// ---------- persistent MFMA LSTM ----------
// 256 wgs x 256 thr. wg<128: layer1 tile; wg>=128: layer0 tile.
// wg tile = 64 gate-rows x 64 batch; wave = 16 rows x 64 batch (4 D-tiles 16x16).
// D layout: col=lane&15 (batch), row=(lane>>4)*4+reg (gate). Rows permuted hcol*4+gate
// => each lane's 4 acc regs are i,f,g,o of one (hcol,batch): cell update lane-local.
// Activations in1{hi,lo}[2][256][1024]: cols 0..511 = h0, 512..1023 = h1, k-major.
__global__ __launch_bounds__(NTHR, 1) void k_lstm(
    const __bf16* __restrict__ xhi, const __bf16* __restrict__ xlo,
    const __bf16* __restrict__ w0hi, const __bf16* __restrict__ w0lo, const float* __restrict__ bias0,
    const __bf16* __restrict__ w1hi, const __bf16* __restrict__ w1lo, const float* __restrict__ bias1,
    __bf16* __restrict__ in1hi, __bf16* __restrict__ in1lo,
    const float* __restrict__ fcw, const float* __restrict__ fcb,
    float* __restrict__ out, unsigned* __restrict__ bar)
{
  const int tid  = threadIdx.x;
  const int lane = tid & 63;
  const int w    = __builtin_amdgcn_readfirstlane(tid >> 6);
  const int wg   = blockIdx.x;
  const int layer1 = (wg < 128) ? 1 : 0;
  const int lw   = wg & 127;
  const int rg   = lw >> 2;            // 0..31 row-group (64 rows)
  const int bg   = lw & 3;             // 0..3 batch-group (64 batch)
  const int rbase = rg * 64 + w * 16;  // gate-row base of this wave
  const int bbase = bg * 64;
  const int lr = lane & 15;            // A-row / B-col / D-col offset
  const int lg = lane >> 4;            // k-subgroup (A/B), row-subgroup (D)

  // zero activation buffers (both parities)
  {
    unsigned* zh = (unsigned*)in1hi;
    unsigned* zl = (unsigned*)in1lo;
    const int n2 = 2 * BATCH * K1 / 2;   // as uint (2 bf16)
    for (int i = wg * NTHR + tid; i < n2; i += NWG * NTHR) { zh[i] = 0u; zl[i] = 0u; }
  }
  grid_barrier(bar, bar + 1);

  const int hc = (rbase >> 2) + lg;    // hidden column this lane owns (per D-tile)
  const float4 b4 = *reinterpret_cast<const float4*>((layer1 ? bias1 : bias0) + hc * 4);
  const int KW = layer1 ? K1 : K0;
  const __bf16* Ahi = (layer1 ? w1hi : w0hi) + (size_t)(rbase + lr) * KW + lg * 8;
  const __bf16* Alo = (layer1 ? w1lo : w0lo) + (size_t)(rbase + lr) * KW + lg * 8;

  float c[4] = {0.f, 0.f, 0.f, 0.f};

  for (int n = 0; n <= T_SEQ; ++n) {
    const int pr = (n + 1) & 1;   // read parity (written in iter n-1)
    const int pw = n & 1;         // write parity
    const bool active = layer1 ? (n >= 1) : (n < T_SEQ);
    if (active) {
      f32x4 acc[4];
      #pragma unroll
      for (int st = 0; st < 4; ++st) { acc[st][0]=b4.x; acc[st][1]=b4.y; acc[st][2]=b4.z; acc[st][3]=b4.w; }

      const __bf16* Bh = in1hi + ((size_t)pr * BATCH + bbase) * K1 + lg * 8;
      const __bf16* Bl = in1lo + ((size_t)pr * BATCH + bbase) * K1 + lg * 8;

      if (layer1) {
        #pragma unroll 2
        for (int ks = 0; ks < 32; ++ks) {
          b16x8 ah = *reinterpret_cast<const b16x8*>(Ahi + ks * 32);
          b16x8 al = *reinterpret_cast<const b16x8*>(Alo + ks * 32);
          #pragma unroll
          for (int st = 0; st < 4; ++st) {
            const size_t bo = (size_t)(st * 16 + lr) * K1 + ks * 32;
            b16x8 bh = *reinterpret_cast<const b16x8*>(Bh + bo);
            b16x8 bl = *reinterpret_cast<const b16x8*>(Bl + bo);
            acc[st] = mfma16(ah, bh, acc[st]);
            acc[st] = mfma16(ah, bl, acc[st]);
            acc[st] = mfma16(al, bh, acc[st]);
          }
        }
      } else {
        const __bf16* Xh = xhi + ((size_t)n * BATCH + bbase) * IN0 + lg * 8;
        const __bf16* Xl = xlo + ((size_t)n * BATCH + bbase) * IN0 + lg * 8;
        #pragma unroll
        for (int ks = 0; ks < 2; ++ks) {            // x part: weight k 0..63
          b16x8 ah = *reinterpret_cast<const b16x8*>(Ahi + ks * 32);
          b16x8 al = *reinterpret_cast<const b16x8*>(Alo + ks * 32);
          #pragma unroll
          for (int st = 0; st < 4; ++st) {
            const size_t bo = (size_t)(st * 16 + lr) * IN0 + ks * 32;
            b16x8 bh = *reinterpret_cast<const b16x8*>(Xh + bo);
            b16x8 bl = *reinterpret_cast<const b16x8*>(Xl + bo);
            acc[st] = mfma16(ah, bh, acc[st]);
            acc[st] = mfma16(ah, bl, acc[st]);
            acc[st] = mfma16(al, bh, acc[st]);
          }
        }
        #pragma unroll 2
        for (int ks = 0; ks < 16; ++ks) {           // h0 part: weight k 64.., in1 col 0..511
          b16x8 ah = *reinterpret_cast<const b16x8*>(Ahi + 64 + ks * 32);
          b16x8 al = *reinterpret_cast<const b16x8*>(Alo + 64 + ks * 32);
          #pragma unroll
          for (int st = 0; st < 4; ++st) {
            const size_t bo = (size_t)(st * 16 + lr) * K1 + ks * 32;
            b16x8 bh = *reinterpret_cast<const b16x8*>(Bh + bo);
            b16x8 bl = *reinterpret_cast<const b16x8*>(Bl + bo);
            acc[st] = mfma16(ah, bh, acc[st]);
            acc[st] = mfma16(ah, bl, acc[st]);
            acc[st] = mfma16(al, bh, acc[st]);
          }
        }
      }

      // ---- lane-local cell update; store h as split bf16 ----
      const int colbase = layer1 ? (512 + hc) : hc;
      #pragma unroll
      for (int st = 0; st < 4; ++st) {
        float i_ = sigm(acc[st][0]);
        float f_ = sigm(acc[st][1]);
        float g_ = tanh_f(acc[st][2]);
        float o_ = sigm(acc[st][3]);
        c[st] = fmaf(f_, c[st], i_ * g_);
        float hv = o_ * tanh_f(c[st]);
        __bf16 hh = (__bf16)hv;
        __bf16 hl = (__bf16)(hv - (float)hh);
        const int b = bbase + st * 16 + lr;
        const size_t idx = ((size_t)pw * BATCH + b) * K1 + colbase;
        in1hi[idx] = hh;
        in1lo[idx] = hl;
      }
    }
    grid_barrier(bar, bar + 1);
  }

  // ---- final FC on h1[511] (parity 512&1 = 0), cols 512..1023 ----
  if (wg == 0) {
    const __bf16* rh = in1hi + (size_t)tid * K1 + 512;
    const __bf16* rl = in1lo + (size_t)tid * K1 + 512;
    float acc = 0.f;
    #pragma unroll 8
    for (int k = 0; k < HID; ++k)
      acc = fmaf((float)rh[k] + (float)rl[k], fcw[k], acc);
    out[tid] = acc + fcb[0];
  }
}

// ---------- host ----------
extern "C" void kernel_launch(void* const* d_in, const int* in_sizes, int n_in,
                              void* d_out, int out_size, void* d_ws, size_t ws_size,
                              hipStream_t stream) {
  const float* x    = (const float*)d_in[0];
  const float* Wih0 = (const float*)d_in[1];
  const float* Whh0 = (const float*)d_in[2];
  const float* bih0 = (const float*)d_in[3];
  const float* bhh0 = (const float*)d_in[4];
  const float* Wih1 = (const float*)d_in[5];
  const float* Whh1 = (const float*)d_in[6];
  const float* bih1 = (const float*)d_in[7];
  const float* bhh1 = (const float*)d_in[8];
  const float* fcw  = (const float*)d_in[9];
  const float* fcb  = (const float*)d_in[10];

  char* ws = (char*)d_ws;
  size_t off = 0;
  auto alloc = [&](size_t bytes) -> char* {
    char* pp = ws + off;
    off = (off + bytes + 1023) & ~(size_t)1023;
    return pp;
  };
  unsigned* bar  = (unsigned*)alloc(256);
  __bf16* xhi  = (__bf16*)alloc((size_t)T_SEQ * BATCH * IN0 * 2);   // 16.8 MB
  __bf16* xlo  = (__bf16*)alloc((size_t)T_SEQ * BATCH * IN0 * 2);
  __bf16* w0hi = (__bf16*)alloc((size_t)2048 * K0 * 2);             // 2.36 MB
  __bf16* w0lo = (__bf16*)alloc((size_t)2048 * K0 * 2);
  __bf16* w1hi = (__bf16*)alloc((size_t)2048 * K1 * 2);             // 4.2 MB
  __bf16* w1lo = (__bf16*)alloc((size_t)2048 * K1 * 2);
  float*  bias0 = (float*)alloc(2048 * 4);
  float*  bias1 = (float*)alloc(2048 * 4);
  __bf16* in1hi = (__bf16*)alloc((size_t)2 * BATCH * K1 * 2);       // 1 MB
  __bf16* in1lo = (__bf16*)alloc((size_t)2 * BATCH * K1 * 2);

  (void)hipMemsetAsync(bar, 0, 256, stream);
  k_split_x<<<(T_SEQ * BATCH * IN0) / 256, 256, 0, stream>>>(x, xhi, xlo);
  k_split_w<<<(int)((2048L * K0 + 255) / 256), 256, 0, stream>>>(Wih0, Whh0, bih0, bhh0, w0hi, w0lo, bias0, IN0);
  k_split_w<<<(int)((2048L * K1 + 255) / 256), 256, 0, stream>>>(Wih1, Whh1, bih1, bhh1, w1hi, w1lo, bias1, HID);
  k_lstm<<<NWG, NTHR, 0, stream>>>(xhi, xlo, w0hi, w0lo, bias0, w1hi, w1lo, bias1,
                                   in1hi, in1lo, fcw, fcb, (float*)d_out, bar);
}

// Round 4
// 28217.596 us; speedup vs baseline: 2.8115x; 2.4782x over previous
//
#include <hip/hip_runtime.h>
#include <math.h>

#define T_SEQ 512
#define BATCH 256
#define HID   512
#define IN0   64
#define K1    1024           /* L1: 512 h0 + 512 h1 */
#define K0    576            /* L0: 64 x + 512 h0   */
#define NWG   256
#define NTHR  256

typedef __bf16 b16x8 __attribute__((ext_vector_type(8)));
typedef float  f32x4 __attribute__((ext_vector_type(4)));

__device__ __forceinline__ float sigm(float x)   { return 1.0f / (1.0f + __expf(-x)); }
__device__ __forceinline__ float tanh_f(float x) { return 2.0f / (1.0f + __expf(-2.0f * x)) - 1.0f; }

__device__ __forceinline__ f32x4 mfma16(b16x8 a, b16x8 b, f32x4 c) {
  return __builtin_amdgcn_mfma_f32_16x16x32_bf16(a, b, c, 0, 0, 0);
}

// ---------- prep: split W into LDS-order layout ----------
// rows permuted r = hcol*4 + gate; k-concat ih|hh.
// out layout: [slice s=r>>4][kc=k>>3][row16=r&15][ke=k&7]  (16-B chunks contiguous)
__global__ void k_split_w(const float* __restrict__ Wih, const float* __restrict__ Whh,
                          const float* __restrict__ bih, const float* __restrict__ bhh,
                          __bf16* __restrict__ whi, __bf16* __restrict__ wlo,
                          float* __restrict__ bias, int Kin) {
  int K = Kin + HID;
  long idx = (long)blockIdx.x * 256 + threadIdx.x;
  long total = 2048L * K;
  if (idx < total) {
    int k = (int)(idx % K);
    int r = (int)(idx / K);
    int gate = r & 3, hcol = r >> 2;
    int row = gate * HID + hcol;
    float v = (k < Kin) ? Wih[(long)row * Kin + k] : Whh[(long)row * HID + (k - Kin)];
    __bf16 h = (__bf16)v;
    long o = (long)(r >> 4) * 16 * K + (long)(k >> 3) * 128 + (r & 15) * 8 + (k & 7);
    whi[o] = h;
    wlo[o] = (__bf16)(v - (float)h);
  }
  if (idx < 2048) {
    int r = (int)idx;
    int gate = r & 3, hcol = r >> 2;
    int row = gate * HID + hcol;
    bias[r] = bih[row] + bhh[row];
  }
}

// ---------- prep: x[B][T][I] -> split bf16 [T][B][I] ----------
__global__ void k_split_x(const float* __restrict__ x,
                          __bf16* __restrict__ xhi, __bf16* __restrict__ xlo) {
  int idx = blockIdx.x * 256 + threadIdx.x;   // dst index, [t][b][i]
  int i = idx & 63;
  int b = (idx >> 6) & 255;
  int t = idx >> 14;
  float v = x[((size_t)b * T_SEQ + t) * IN0 + i];
  __bf16 h = (__bf16)v;
  xhi[idx] = h;
  xlo[idx] = (__bf16)(v - (float)h);
}

// ---------- device-scope grid barrier: RELAXED spin, one fence per side ----------
__device__ __forceinline__ void grid_barrier(unsigned* cnt, unsigned* gen) {
  __syncthreads();
  if (threadIdx.x == 0) {
    __threadfence();  // release: wbl2 once
    unsigned g = __hip_atomic_load(gen, __ATOMIC_RELAXED, __HIP_MEMORY_SCOPE_AGENT);
    unsigned arrived = __hip_atomic_fetch_add(cnt, 1u, __ATOMIC_RELAXED, __HIP_MEMORY_SCOPE_AGENT);
    if (arrived == NWG - 1) {
      __hip_atomic_store(cnt, 0u, __ATOMIC_RELAXED, __HIP_MEMORY_SCOPE_AGENT);
      __hip_atomic_fetch_add(gen, 1u, __ATOMIC_RELAXED, __HIP_MEMORY_SCOPE_AGENT);
    } else {
      while (__hip_atomic_load(gen, __ATOMIC_RELAXED, __HIP_MEMORY_SCOPE_AGENT) == g) {
        __builtin_amdgcn_s_sleep(2);
      }
    }
    __threadfence();  // acquire: inv once
  }
  __syncthreads();
}

// ---------- persistent MFMA LSTM ----------
// 256 wgs x 256 thr. wg<128: layer1 rows wg*16..+15; wg>=128: layer0 rows (wg-128)*16..+15.
// All 256 batch per wg; wave wv covers batch wv*64..+63 (4 MFMA D-tiles of 16 cols).
// Weights (split hi/lo) for the wg's 16 rows live in LDS, loaded ONCE.
// D layout: col=lane&15 (batch), row=(lane>>4)*4+reg. Rows permuted hcol*4+gate =>
// lane's 4 acc regs = i,f,g,o of one (hcol,batch): cell update lane-local, c in regs.
// Activations in1{hi,lo}[2][256][1024]: cols 0..511 = h0, 512..1023 = h1, k-major.
__global__ __launch_bounds__(NTHR, 1) void k_lstm(
    const __bf16* __restrict__ xhi, const __bf16* __restrict__ xlo,
    const __bf16* __restrict__ w0hi, const __bf16* __restrict__ w0lo, const float* __restrict__ bias0,
    const __bf16* __restrict__ w1hi, const __bf16* __restrict__ w1lo, const float* __restrict__ bias1,
    __bf16* __restrict__ in1hi, __bf16* __restrict__ in1lo,
    const float* __restrict__ fcw, const float* __restrict__ fcb,
    float* __restrict__ out, unsigned* __restrict__ bar)
{
  __shared__ __align__(16) __bf16 ldsA[2][16 * K1];   // [hi/lo][kc][row16][8] = 64 KB

  const int tid  = threadIdx.x;
  const int lane = tid & 63;
  const int wv   = __builtin_amdgcn_readfirstlane(tid >> 6);
  const int wg   = blockIdx.x;
  const int layer1 = (wg < 128) ? 1 : 0;
  const int lw   = wg & 127;
  const int bbase = wv * 64;
  const int lr = lane & 15;            // A-row16 / B-batch / D-col offset
  const int lg = lane >> 4;            // k-subgroup (A/B), row-subgroup (D)
  const int KW = layer1 ? K1 : K0;

  // ---- one-time: load this wg's weight slice into LDS (coalesced memcpy) ----
  {
    const b16x8* gh = reinterpret_cast<const b16x8*>((layer1 ? w1hi : w0hi) + (size_t)lw * 16 * KW);
    const b16x8* gl = reinterpret_cast<const b16x8*>((layer1 ? w1lo : w0lo) + (size_t)lw * 16 * KW);
    b16x8* lh = reinterpret_cast<b16x8*>(ldsA[0]);
    b16x8* ll = reinterpret_cast<b16x8*>(ldsA[1]);
    const int nch = 2 * KW;            // 16*KW/8 chunks of 16 B
    for (int ch = tid; ch < nch; ch += NTHR) { lh[ch] = gh[ch]; ll[ch] = gl[ch]; }
  }

  // ---- zero activation buffers (both parities) ----
  {
    unsigned* zh = (unsigned*)in1hi;
    unsigned* zl = (unsigned*)in1lo;
    const int n2 = 2 * BATCH * K1 / 2;
    for (int i = wg * NTHR + tid; i < n2; i += NWG * NTHR) { zh[i] = 0u; zl[i] = 0u; }
  }
  __syncthreads();
  grid_barrier(bar, bar + 1);

  const int hc = lw * 4 + lg;          // hidden column this lane owns
  const float4 b4 = *reinterpret_cast<const float4*>((layer1 ? bias1 : bias0) + hc * 4);
  const b16x8* Ah = reinterpret_cast<const b16x8*>(ldsA[0]);
  const b16x8* Al = reinterpret_cast<const b16x8*>(ldsA[1]);

  float c[4] = {0.f, 0.f, 0.f, 0.f};

  #pragma unroll 1
  for (int n = 0; n <= T_SEQ; ++n) {
    const int pr = (n + 1) & 1;   // read parity
    const int pw = n & 1;         // write parity
    const bool active = layer1 ? (n >= 1) : (n < T_SEQ);
    if (active) {
      f32x4 acc[4];
      #pragma unroll
      for (int st = 0; st < 4; ++st) { acc[st][0]=b4.x; acc[st][1]=b4.y; acc[st][2]=b4.z; acc[st][3]=b4.w; }

      const __bf16* Bh = in1hi + ((size_t)pr * BATCH + bbase) * K1 + lg * 8;
      const __bf16* Bl = in1lo + ((size_t)pr * BATCH + bbase) * K1 + lg * 8;

      if (layer1) {
        #pragma unroll 4
        for (int ks = 0; ks < 32; ++ks) {
          b16x8 ah = Ah[(ks * 4 + lg) * 16 + lr];
          b16x8 al = Al[(ks * 4 + lg) * 16 + lr];
          #pragma unroll
          for (int st = 0; st < 4; ++st) {
            const size_t bo = (size_t)(st * 16 + lr) * K1 + ks * 32;
            b16x8 bh = *reinterpret_cast<const b16x8*>(Bh + bo);
            b16x8 bl = *reinterpret_cast<const b16x8*>(Bl + bo);
            acc[st] = mfma16(ah, bh, acc[st]);
            acc[st] = mfma16(ah, bl, acc[st]);
            acc[st] = mfma16(al, bh, acc[st]);
          }
        }
      } else {
        const __bf16* Xh = xhi + ((size_t)n * BATCH + bbase) * IN0 + lg * 8;
        const __bf16* Xl = xlo + ((size_t)n * BATCH + bbase) * IN0 + lg * 8;
        #pragma unroll
        for (int ks = 0; ks < 2; ++ks) {            // x part: k 0..63
          b16x8 ah = Ah[(ks * 4 + lg) * 16 + lr];
          b16x8 al = Al[(ks * 4 + lg) * 16 + lr];
          #pragma unroll
          for (int st = 0; st < 4; ++st) {
            const size_t bo = (size_t)(st * 16 + lr) * IN0 + ks * 32;
            b16x8 bh = *reinterpret_cast<const b16x8*>(Xh + bo);
            b16x8 bl = *reinterpret_cast<const b16x8*>(Xl + bo);
            acc[st] = mfma16(ah, bh, acc[st]);
            acc[st] = mfma16(ah, bl, acc[st]);
            acc[st] = mfma16(al, bh, acc[st]);
          }
        }
        #pragma unroll 4
        for (int ks = 0; ks < 16; ++ks) {           // h0 part: weight k 64.., in1 cols 0..511
          b16x8 ah = Ah[((8 + ks * 4) + lg) * 16 + lr];
          b16x8 al = Al[((8 + ks * 4) + lg) * 16 + lr];
          #pragma unroll
          for (int st = 0; st < 4; ++st) {
            const size_t bo = (size_t)(st * 16 + lr) * K1 + ks * 32;
            b16x8 bh = *reinterpret_cast<const b16x8*>(Bh + bo);
            b16x8 bl = *reinterpret_cast<const b16x8*>(Bl + bo);
            acc[st] = mfma16(ah, bh, acc[st]);
            acc[st] = mfma16(ah, bl, acc[st]);
            acc[st] = mfma16(al, bh, acc[st]);
          }
        }
      }

      // ---- lane-local cell update; store h as split bf16 ----
      const int colbase = layer1 ? (512 + hc) : hc;
      #pragma unroll
      for (int st = 0; st < 4; ++st) {
        float i_ = sigm(acc[st][0]);
        float f_ = sigm(acc[st][1]);
        float g_ = tanh_f(acc[st][2]);
        float o_ = sigm(acc[st][3]);
        c[st] = fmaf(f_, c[st], i_ * g_);
        float hv = o_ * tanh_f(c[st]);
        __bf16 hh = (__bf16)hv;
        __bf16 hl = (__bf16)(hv - (float)hh);
        const int b = bbase + st * 16 + lr;
        const size_t idx = ((size_t)pw * BATCH + b) * K1 + colbase;
        in1hi[idx] = hh;
        in1lo[idx] = hl;
      }
    }
    grid_barrier(bar, bar + 1);
  }

  // ---- final FC on h1[511] (written at iter 512, parity 0), cols 512..1023 ----
  if (wg == 0) {
    const __bf16* rh = in1hi + (size_t)tid * K1 + 512;
    const __bf16* rl = in1lo + (size_t)tid * K1 + 512;
    float acc = 0.f;
    #pragma unroll 8
    for (int k = 0; k < HID; ++k)
      acc = fmaf((float)rh[k] + (float)rl[k], fcw[k], acc);
    out[tid] = acc + fcb[0];
  }
}

// ---------- host ----------
extern "C" void kernel_launch(void* const* d_in, const int* in_sizes, int n_in,
                              void* d_out, int out_size, void* d_ws, size_t ws_size,
                              hipStream_t stream) {
  const float* x    = (const float*)d_in[0];
  const float* Wih0 = (const float*)d_in[1];
  const float* Whh0 = (const float*)d_in[2];
  const float* bih0 = (const float*)d_in[3];
  const float* bhh0 = (const float*)d_in[4];
  const float* Wih1 = (const float*)d_in[5];
  const float* Whh1 = (const float*)d_in[6];
  const float* bih1 = (const float*)d_in[7];
  const float* bhh1 = (const float*)d_in[8];
  const float* fcw  = (const float*)d_in[9];
  const float* fcb  = (const float*)d_in[10];

  char* ws = (char*)d_ws;
  size_t off = 0;
  auto alloc = [&](size_t bytes) -> char* {
    char* pp = ws + off;
    off = (off + bytes + 1023) & ~(size_t)1023;
    return pp;
  };
  unsigned* bar  = (unsigned*)alloc(256);
  __bf16* xhi  = (__bf16*)alloc((size_t)T_SEQ * BATCH * IN0 * 2);   // 16.8 MB
  __bf16* xlo  = (__bf16*)alloc((size_t)T_SEQ * BATCH * IN0 * 2);
  __bf16* w0hi = (__bf16*)alloc((size_t)2048 * K0 * 2);             // 2.36 MB
  __bf16* w0lo = (__bf16*)alloc((size_t)2048 * K0 * 2);
  __bf16* w1hi = (__bf16*)alloc((size_t)2048 * K1 * 2);             // 4.2 MB
  __bf16* w1lo = (__bf16*)alloc((size_t)2048 * K1 * 2);
  float*  bias0 = (float*)alloc(2048 * 4);
  float*  bias1 = (float*)alloc(2048 * 4);
  __bf16* in1hi = (__bf16*)alloc((size_t)2 * BATCH * K1 * 2);       // 1 MB
  __bf16* in1lo = (__bf16*)alloc((size_t)2 * BATCH * K1 * 2);

  (void)hipMemsetAsync(bar, 0, 256, stream);
  k_split_x<<<(T_SEQ * BATCH * IN0) / 256, 256, 0, stream>>>(x, xhi, xlo);
  k_split_w<<<(int)((2048L * K0 + 255) / 256), 256, 0, stream>>>(Wih0, Whh0, bih0, bhh0, w0hi, w0lo, bias0, IN0);
  k_split_w<<<(int)((2048L * K1 + 255) / 256), 256, 0, stream>>>(Wih1, Whh1, bih1, bhh1, w1hi, w1lo, bias1, HID);
  k_lstm<<<NWG, NTHR, 0, stream>>>(xhi, xlo, w0hi, w0lo, bias0, w1hi, w1lo, bias1,
                                   in1hi, in1lo, fcw, fcb, (float*)d_out, bar);
}

// Round 5
// 19901.640 us; speedup vs baseline: 3.9863x; 1.4179x over previous
//
#include <hip/hip_runtime.h>
#include <math.h>

#define T_SEQ 512
#define BATCH 256
#define HID   512
#define IN0   64
#define K1    1024           /* L1: 512 h0 + 512 h1 */
#define K0    576            /* L0: 64 x + 512 h0   */
#define NWG   256
#define NTHR  256

typedef __bf16 b16x8 __attribute__((ext_vector_type(8)));
typedef float  f32x4 __attribute__((ext_vector_type(4)));

__device__ __forceinline__ float sigm(float x)   { return 1.0f / (1.0f + __expf(-x)); }
__device__ __forceinline__ float tanh_f(float x) { return 2.0f / (1.0f + __expf(-2.0f * x)) - 1.0f; }

__device__ __forceinline__ f32x4 mfma16(b16x8 a, b16x8 b, f32x4 c) {
  return __builtin_amdgcn_mfma_f32_16x16x32_bf16(a, b, c, 0, 0, 0);
}

// write-through store to the coherence point (no dirty L2 anywhere)
__device__ __forceinline__ void store_short_wt(const __bf16* p, unsigned v) {
  asm volatile("global_store_short %0, %1, off sc0 sc1"
               :: "v"((const void*)p), "v"(v) : "memory");
}

// ---------- prep: split W into LDS-order layout ----------
// rows permuted r = hcol*4 + gate; k-concat ih|hh.
// out layout: [slice s=r>>4][kc=k>>3][row16=r&15][ke=k&7]  (16-B chunks contiguous)
__global__ void k_split_w(const float* __restrict__ Wih, const float* __restrict__ Whh,
                          const float* __restrict__ bih, const float* __restrict__ bhh,
                          __bf16* __restrict__ whi, __bf16* __restrict__ wlo,
                          float* __restrict__ bias, int Kin) {
  int K = Kin + HID;
  long idx = (long)blockIdx.x * 256 + threadIdx.x;
  long total = 2048L * K;
  if (idx < total) {
    int k = (int)(idx % K);
    int r = (int)(idx / K);
    int gate = r & 3, hcol = r >> 2;
    int row = gate * HID + hcol;
    float v = (k < Kin) ? Wih[(long)row * Kin + k] : Whh[(long)row * HID + (k - Kin)];
    __bf16 h = (__bf16)v;
    long o = (long)(r >> 4) * 16 * K + (long)(k >> 3) * 128 + (r & 15) * 8 + (k & 7);
    whi[o] = h;
    wlo[o] = (__bf16)(v - (float)h);
  }
  if (idx < 2048) {
    int r = (int)idx;
    int gate = r & 3, hcol = r >> 2;
    int row = gate * HID + hcol;
    bias[r] = bih[row] + bhh[row];
  }
}

// ---------- prep: x[B][T][I] -> split bf16 [T][B][I] ----------
__global__ void k_split_x(const float* __restrict__ x,
                          __bf16* __restrict__ xhi, __bf16* __restrict__ xlo) {
  int idx = blockIdx.x * 256 + threadIdx.x;   // dst index, [t][b][i]
  int i = idx & 63;
  int b = (idx >> 6) & 255;
  int t = idx >> 14;
  float v = x[((size_t)b * T_SEQ + t) * IN0 + i];
  __bf16 h = (__bf16)v;
  xhi[idx] = h;
  xlo[idx] = (__bf16)(v - (float)h);
}

// ---------- grid barrier: monotonic gen counter, acquire-only fence ----------
// release ordering is provided by the callers' s_waitcnt vmcnt(0) after
// write-through (sc0 sc1) stores: nothing is ever dirty in L2.
__device__ __forceinline__ void grid_barrier(unsigned* gen, unsigned target) {
  __syncthreads();
  if (threadIdx.x == 0) {
    __hip_atomic_fetch_add(gen, 1u, __ATOMIC_RELAXED, __HIP_MEMORY_SCOPE_AGENT);
    while ((int)(__hip_atomic_load(gen, __ATOMIC_RELAXED, __HIP_MEMORY_SCOPE_AGENT) - target) < 0)
      __builtin_amdgcn_s_sleep(2);
    __builtin_amdgcn_fence(__ATOMIC_ACQUIRE, "agent");   // buffer_inv only
  }
  __syncthreads();
}

// ---------- persistent MFMA LSTM ----------
// 256 wgs x 256 thr. wg<128: layer1 rows wg*16..+15; wg>=128: layer0 rows (wg-128)*16..+15.
// All 256 batch per wg; wave wv covers batch wv*64..+63 (4 MFMA D-tiles of 16 cols).
// Weights (split hi/lo) for the wg's 16 rows live in LDS, loaded ONCE.
// D layout: col=lane&15 (batch), row=(lane>>4)*4+reg. Rows permuted hcol*4+gate =>
// lane's 4 acc regs = i,f,g,o of one (hcol,batch): cell update lane-local, c in regs.
// Activations in1{hi,lo}[2][256][1024]: cols 0..511 = h0, 512..1023 = h1, k-major.
__global__ __launch_bounds__(NTHR, 1) void k_lstm(
    const __bf16* __restrict__ xhi, const __bf16* __restrict__ xlo,
    const __bf16* __restrict__ w0hi, const __bf16* __restrict__ w0lo, const float* __restrict__ bias0,
    const __bf16* __restrict__ w1hi, const __bf16* __restrict__ w1lo, const float* __restrict__ bias1,
    __bf16* __restrict__ in1hi, __bf16* __restrict__ in1lo,
    const float* __restrict__ fcw, const float* __restrict__ fcb,
    float* __restrict__ out, unsigned* __restrict__ bar)
{
  __shared__ __align__(16) __bf16 ldsA[2][16 * K1];   // [hi/lo][kc][row16][8] = 64 KB

  const int tid  = threadIdx.x;
  const int lane = tid & 63;
  const int wv   = __builtin_amdgcn_readfirstlane(tid >> 6);
  const int wg   = blockIdx.x;
  const int layer1 = (wg < 128) ? 1 : 0;
  const int lw   = wg & 127;
  const int bbase = wv * 64;
  const int lr = lane & 15;            // A-row16 / B-batch / D-col offset
  const int lg = lane >> 4;            // k-subgroup (A/B), row-subgroup (D)
  const int KW = layer1 ? K1 : K0;

  // ---- one-time: load this wg's weight slice into LDS (coalesced memcpy) ----
  {
    const b16x8* gh = reinterpret_cast<const b16x8*>((layer1 ? w1hi : w0hi) + (size_t)lw * 16 * KW);
    const b16x8* gl = reinterpret_cast<const b16x8*>((layer1 ? w1lo : w0lo) + (size_t)lw * 16 * KW);
    b16x8* lh = reinterpret_cast<b16x8*>(ldsA[0]);
    b16x8* ll = reinterpret_cast<b16x8*>(ldsA[1]);
    const int nch = 2 * KW;            // 16*KW/8 chunks of 16 B
    for (int ch = tid; ch < nch; ch += NTHR) { lh[ch] = gh[ch]; ll[ch] = gl[ch]; }
  }
  __syncthreads();

  const int hc = lw * 4 + lg;          // hidden column this lane owns
  const float4 b4 = *reinterpret_cast<const float4*>((layer1 ? bias1 : bias0) + hc * 4);
  const b16x8* Ah = reinterpret_cast<const b16x8*>(ldsA[0]);
  const b16x8* Al = reinterpret_cast<const b16x8*>(ldsA[1]);

  float c[4] = {0.f, 0.f, 0.f, 0.f};

  #pragma unroll 1
  for (int n = 0; n <= T_SEQ; ++n) {
    const int pr = (n + 1) & 1;   // read parity
    const int pw = n & 1;         // write parity
    const bool active = layer1 ? (n >= 1) : (n < T_SEQ);
    if (active) {
      f32x4 acc[4];
      #pragma unroll
      for (int st = 0; st < 4; ++st) { acc[st][0]=b4.x; acc[st][1]=b4.y; acc[st][2]=b4.z; acc[st][3]=b4.w; }

      const __bf16* Bh = in1hi + ((size_t)pr * BATCH + bbase) * K1 + lg * 8;
      const __bf16* Bl = in1lo + ((size_t)pr * BATCH + bbase) * K1 + lg * 8;

      if (layer1) {
        #pragma unroll 4
        for (int ks = 0; ks < 32; ++ks) {
          b16x8 ah = Ah[(ks * 4 + lg) * 16 + lr];
          b16x8 al = Al[(ks * 4 + lg) * 16 + lr];
          #pragma unroll
          for (int st = 0; st < 4; ++st) {
            const size_t bo = (size_t)(st * 16 + lr) * K1 + ks * 32;
            b16x8 bh = *reinterpret_cast<const b16x8*>(Bh + bo);
            b16x8 bl = *reinterpret_cast<const b16x8*>(Bl + bo);
            acc[st] = mfma16(ah, bh, acc[st]);
            acc[st] = mfma16(ah, bl, acc[st]);
            acc[st] = mfma16(al, bh, acc[st]);
          }
        }
      } else {
        const __bf16* Xh = xhi + ((size_t)n * BATCH + bbase) * IN0 + lg * 8;
        const __bf16* Xl = xlo + ((size_t)n * BATCH + bbase) * IN0 + lg * 8;
        #pragma unroll
        for (int ks = 0; ks < 2; ++ks) {            // x part: k 0..63
          b16x8 ah = Ah[(ks * 4 + lg) * 16 + lr];
          b16x8 al = Al[(ks * 4 + lg) * 16 + lr];
          #pragma unroll
          for (int st = 0; st < 4; ++st) {
            const size_t bo = (size_t)(st * 16 + lr) * IN0 + ks * 32;
            b16x8 bh = *reinterpret_cast<const b16x8*>(Xh + bo);
            b16x8 bl = *reinterpret_cast<const b16x8*>(Xl + bo);
            acc[st] = mfma16(ah, bh, acc[st]);
            acc[st] = mfma16(ah, bl, acc[st]);
            acc[st] = mfma16(al, bh, acc[st]);
          }
        }
        #pragma unroll 4
        for (int ks = 0; ks < 16; ++ks) {           // h0 part: weight k 64.., in1 cols 0..511
          b16x8 ah = Ah[((8 + ks * 4) + lg) * 16 + lr];
          b16x8 al = Al[((8 + ks * 4) + lg) * 16 + lr];
          #pragma unroll
          for (int st = 0; st < 4; ++st) {
            const size_t bo = (size_t)(st * 16 + lr) * K1 + ks * 32;
            b16x8 bh = *reinterpret_cast<const b16x8*>(Bh + bo);
            b16x8 bl = *reinterpret_cast<const b16x8*>(Bl + bo);
            acc[st] = mfma16(ah, bh, acc[st]);
            acc[st] = mfma16(ah, bl, acc[st]);
            acc[st] = mfma16(al, bh, acc[st]);
          }
        }
      }

      // ---- lane-local cell update; write-through split-bf16 h stores ----
      const int colbase = layer1 ? (512 + hc) : hc;
      #pragma unroll
      for (int st = 0; st < 4; ++st) {
        float i_ = sigm(acc[st][0]);
        float f_ = sigm(acc[st][1]);
        float g_ = tanh_f(acc[st][2]);
        float o_ = sigm(acc[st][3]);
        c[st] = fmaf(f_, c[st], i_ * g_);
        float hv = o_ * tanh_f(c[st]);
        __bf16 hh = (__bf16)hv;
        __bf16 hl = (__bf16)(hv - (float)hh);
        const int b = bbase + st * 16 + lr;
        const size_t idx = ((size_t)pw * BATCH + b) * K1 + colbase;
        store_short_wt(in1hi + idx, (unsigned)__builtin_bit_cast(unsigned short, hh));
        store_short_wt(in1lo + idx, (unsigned)__builtin_bit_cast(unsigned short, hl));
      }
      asm volatile("s_waitcnt vmcnt(0)" ::: "memory");  // release: stores at coherence point
    }
    grid_barrier(bar, (unsigned)(n + 1) * NWG);
  }

  // ---- final FC on h1[511] (written at iter 512, parity 0), cols 512..1023 ----
  if (wg == 0) {
    const __bf16* rh = in1hi + (size_t)tid * K1 + 512;
    const __bf16* rl = in1lo + (size_t)tid * K1 + 512;
    float acc = 0.f;
    #pragma unroll 8
    for (int k = 0; k < HID; ++k)
      acc = fmaf((float)rh[k] + (float)rl[k], fcw[k], acc);
    out[tid] = acc + fcb[0];
  }
}

// ---------- host ----------
extern "C" void kernel_launch(void* const* d_in, const int* in_sizes, int n_in,
                              void* d_out, int out_size, void* d_ws, size_t ws_size,
                              hipStream_t stream) {
  const float* x    = (const float*)d_in[0];
  const float* Wih0 = (const float*)d_in[1];
  const float* Whh0 = (const float*)d_in[2];
  const float* bih0 = (const float*)d_in[3];
  const float* bhh0 = (const float*)d_in[4];
  const float* Wih1 = (const float*)d_in[5];
  const float* Whh1 = (const float*)d_in[6];
  const float* bih1 = (const float*)d_in[7];
  const float* bhh1 = (const float*)d_in[8];
  const float* fcw  = (const float*)d_in[9];
  const float* fcb  = (const float*)d_in[10];

  char* ws = (char*)d_ws;
  size_t off = 0;
  auto alloc = [&](size_t bytes) -> char* {
    char* pp = ws + off;
    off = (off + bytes + 1023) & ~(size_t)1023;
    return pp;
  };
  unsigned* bar  = (unsigned*)alloc(256);
  __bf16* xhi  = (__bf16*)alloc((size_t)T_SEQ * BATCH * IN0 * 2);   // 16.8 MB
  __bf16* xlo  = (__bf16*)alloc((size_t)T_SEQ * BATCH * IN0 * 2);
  __bf16* w0hi = (__bf16*)alloc((size_t)2048 * K0 * 2);             // 2.36 MB
  __bf16* w0lo = (__bf16*)alloc((size_t)2048 * K0 * 2);
  __bf16* w1hi = (__bf16*)alloc((size_t)2048 * K1 * 2);             // 4.2 MB
  __bf16* w1lo = (__bf16*)alloc((size_t)2048 * K1 * 2);
  float*  bias0 = (float*)alloc(2048 * 4);
  float*  bias1 = (float*)alloc(2048 * 4);
  __bf16* in1hi = (__bf16*)alloc((size_t)2 * BATCH * K1 * 2);       // 1 MB
  __bf16* in1lo = (__bf16*)alloc((size_t)2 * BATCH * K1 * 2);

  (void)hipMemsetAsync(bar, 0, 256, stream);
  (void)hipMemsetAsync(in1hi, 0, (size_t)2 * BATCH * K1 * 2, stream);
  (void)hipMemsetAsync(in1lo, 0, (size_t)2 * BATCH * K1 * 2, stream);
  k_split_x<<<(T_SEQ * BATCH * IN0) / 256, 256, 0, stream>>>(x, xhi, xlo);
  k_split_w<<<(int)((2048L * K0 + 255) / 256), 256, 0, stream>>>(Wih0, Whh0, bih0, bhh0, w0hi, w0lo, bias0, IN0);
  k_split_w<<<(int)((2048L * K1 + 255) / 256), 256, 0, stream>>>(Wih1, Whh1, bih1, bhh1, w1hi, w1lo, bias1, HID);
  k_lstm<<<NWG, NTHR, 0, stream>>>(xhi, xlo, w0hi, w0lo, bias0, w1hi, w1lo, bias1,
                                   in1hi, in1lo, fcw, fcb, (float*)d_out, bar);
}

// Round 6
// 19359.590 us; speedup vs baseline: 4.0980x; 1.0280x over previous
//
#include <hip/hip_runtime.h>
#include <math.h>

#define T_SEQ 512
#define BATCH 256
#define HID   512
#define IN0   64
#define K1    1024           /* L1: 512 h0 + 512 h1 */
#define K0    576            /* L0: 64 x + 512 h0   */
#define NWG   256
#define NTHR  512

typedef __bf16 b16x8 __attribute__((ext_vector_type(8)));
typedef float  f32x4 __attribute__((ext_vector_type(4)));

__device__ __forceinline__ float sigm(float x)   { return 1.0f / (1.0f + __expf(-x)); }
__device__ __forceinline__ float tanh_f(float x) { return 2.0f / (1.0f + __expf(-2.0f * x)) - 1.0f; }

__device__ __forceinline__ f32x4 mfma16(b16x8 a, b16x8 b, f32x4 c) {
  return __builtin_amdgcn_mfma_f32_16x16x32_bf16(a, b, c, 0, 0, 0);
}

// write-through store to the coherence point (no dirty L2 anywhere)
__device__ __forceinline__ void store_short_wt(const __bf16* p, unsigned v) {
  asm volatile("global_store_short %0, %1, off sc0 sc1"
               :: "v"((const void*)p), "v"(v) : "memory");
}

// ---------- prep: split W into LDS-order layout ----------
// rows permuted r = hcol*4 + gate; k-concat ih|hh.
// out layout: [slice s=r>>4][kc=k>>3][row16=r&15][ke=k&7]  (16-B chunks contiguous)
__global__ void k_split_w(const float* __restrict__ Wih, const float* __restrict__ Whh,
                          const float* __restrict__ bih, const float* __restrict__ bhh,
                          __bf16* __restrict__ whi, __bf16* __restrict__ wlo,
                          float* __restrict__ bias, int Kin) {
  int K = Kin + HID;
  long idx = (long)blockIdx.x * 256 + threadIdx.x;
  long total = 2048L * K;
  if (idx < total) {
    int k = (int)(idx % K);
    int r = (int)(idx / K);
    int gate = r & 3, hcol = r >> 2;
    int row = gate * HID + hcol;
    float v = (k < Kin) ? Wih[(long)row * Kin + k] : Whh[(long)row * HID + (k - Kin)];
    __bf16 h = (__bf16)v;
    long o = (long)(r >> 4) * 16 * K + (long)(k >> 3) * 128 + (r & 15) * 8 + (k & 7);
    whi[o] = h;
    wlo[o] = (__bf16)(v - (float)h);
  }
  if (idx < 2048) {
    int r = (int)idx;
    int gate = r & 3, hcol = r >> 2;
    int row = gate * HID + hcol;
    bias[r] = bih[row] + bhh[row];
  }
}

// ---------- prep: x[B][T][I] -> split bf16 [T][B][I] ----------
__global__ void k_split_x(const float* __restrict__ x,
                          __bf16* __restrict__ xhi, __bf16* __restrict__ xlo) {
  int idx = blockIdx.x * 256 + threadIdx.x;   // dst index, [t][b][i]
  int i = idx & 63;
  int b = (idx >> 6) & 255;
  int t = idx >> 14;
  float v = x[((size_t)b * T_SEQ + t) * IN0 + i];
  __bf16 h = (__bf16)v;
  xhi[idx] = h;
  xlo[idx] = (__bf16)(v - (float)h);
}

// ---------- grid barrier: monotonic gen counter, acquire-only fence ----------
// release ordering is provided by the callers' s_waitcnt vmcnt(0) after
// write-through (sc0 sc1) stores: nothing is ever dirty in L2.
__device__ __forceinline__ void grid_barrier(unsigned* gen, unsigned target) {
  __syncthreads();
  if (threadIdx.x == 0) {
    __hip_atomic_fetch_add(gen, 1u, __ATOMIC_RELAXED, __HIP_MEMORY_SCOPE_AGENT);
    while ((int)(__hip_atomic_load(gen, __ATOMIC_RELAXED, __HIP_MEMORY_SCOPE_AGENT) - target) < 0)
      __builtin_amdgcn_s_sleep(2);
    __builtin_amdgcn_fence(__ATOMIC_ACQUIRE, "agent");   // buffer_inv only
  }
  __syncthreads();
}

// ---------- persistent MFMA LSTM ----------
// 256 wgs x 512 thr (8 waves, 2/SIMD). wg<128: layer1 rows wg*16..+15;
// wg>=128: layer0 rows (wg-128)*16..+15.
// Wave wv covers batch wv*32..+31 (2 MFMA D-tiles of 16 cols) -> acc[2], c[2].
// Weights (split hi/lo) for the wg's 16 rows live in LDS, loaded ONCE.
// D layout: col=lane&15 (batch), row=(lane>>4)*4+reg. Rows permuted hcol*4+gate =>
// lane's 4 acc regs = i,f,g,o of one (hcol,batch): cell update lane-local, c in regs.
// Activations in1{hi,lo}[2][256][1024]: cols 0..511 = h0, 512..1023 = h1, k-major.
__global__ __launch_bounds__(NTHR, 1) void k_lstm(
    const __bf16* __restrict__ xhi, const __bf16* __restrict__ xlo,
    const __bf16* __restrict__ w0hi, const __bf16* __restrict__ w0lo, const float* __restrict__ bias0,
    const __bf16* __restrict__ w1hi, const __bf16* __restrict__ w1lo, const float* __restrict__ bias1,
    __bf16* __restrict__ in1hi, __bf16* __restrict__ in1lo,
    const float* __restrict__ fcw, const float* __restrict__ fcb,
    float* __restrict__ out, unsigned* __restrict__ bar)
{
  __shared__ __align__(16) __bf16 ldsA[2][16 * K1];   // [hi/lo][kc][row16][8] = 64 KB

  const int tid  = threadIdx.x;
  const int lane = tid & 63;
  const int wv   = __builtin_amdgcn_readfirstlane(tid >> 6);   // 0..7
  const int wg   = blockIdx.x;
  const int layer1 = (wg < 128) ? 1 : 0;
  const int lw   = wg & 127;
  const int bbase = wv * 32;
  const int lr = lane & 15;            // A-row16 / B-batch / D-col offset
  const int lg = lane >> 4;            // k-subgroup (A/B), row-subgroup (D)
  const int KW = layer1 ? K1 : K0;

  // ---- one-time: load this wg's weight slice into LDS (coalesced memcpy) ----
  {
    const b16x8* gh = reinterpret_cast<const b16x8*>((layer1 ? w1hi : w0hi) + (size_t)lw * 16 * KW);
    const b16x8* gl = reinterpret_cast<const b16x8*>((layer1 ? w1lo : w0lo) + (size_t)lw * 16 * KW);
    b16x8* lh = reinterpret_cast<b16x8*>(ldsA[0]);
    b16x8* ll = reinterpret_cast<b16x8*>(ldsA[1]);
    const int nch = 2 * KW;            // 16*KW/8 chunks of 16 B
    for (int ch = tid; ch < nch; ch += NTHR) { lh[ch] = gh[ch]; ll[ch] = gl[ch]; }
  }
  __syncthreads();

  const int hc = lw * 4 + lg;          // hidden column this lane owns
  const float4 b4 = *reinterpret_cast<const float4*>((layer1 ? bias1 : bias0) + hc * 4);
  const b16x8* Ah = reinterpret_cast<const b16x8*>(ldsA[0]);
  const b16x8* Al = reinterpret_cast<const b16x8*>(ldsA[1]);

  float c[2] = {0.f, 0.f};

  #pragma unroll 1
  for (int n = 0; n <= T_SEQ; ++n) {
    const int pr = (n + 1) & 1;   // read parity
    const int pw = n & 1;         // write parity
    const bool active = layer1 ? (n >= 1) : (n < T_SEQ);
    if (active) {
      f32x4 acc[2];
      #pragma unroll
      for (int st = 0; st < 2; ++st) { acc[st][0]=b4.x; acc[st][1]=b4.y; acc[st][2]=b4.z; acc[st][3]=b4.w; }

      const __bf16* Bh = in1hi + ((size_t)pr * BATCH + bbase) * K1 + lg * 8;
      const __bf16* Bl = in1lo + ((size_t)pr * BATCH + bbase) * K1 + lg * 8;

      if (layer1) {
        #pragma unroll 4
        for (int ks = 0; ks < 32; ++ks) {
          b16x8 ah = Ah[(ks * 4 + lg) * 16 + lr];
          b16x8 al = Al[(ks * 4 + lg) * 16 + lr];
          #pragma unroll
          for (int st = 0; st < 2; ++st) {
            const size_t bo = (size_t)(st * 16 + lr) * K1 + ks * 32;
            b16x8 bh = *reinterpret_cast<const b16x8*>(Bh + bo);
            b16x8 bl = *reinterpret_cast<const b16x8*>(Bl + bo);
            acc[st] = mfma16(ah, bh, acc[st]);
            acc[st] = mfma16(ah, bl, acc[st]);
            acc[st] = mfma16(al, bh, acc[st]);
          }
        }
      } else {
        const __bf16* Xh = xhi + ((size_t)n * BATCH + bbase) * IN0 + lg * 8;
        const __bf16* Xl = xlo + ((size_t)n * BATCH + bbase) * IN0 + lg * 8;
        #pragma unroll
        for (int ks = 0; ks < 2; ++ks) {            // x part: k 0..63
          b16x8 ah = Ah[(ks * 4 + lg) * 16 + lr];
          b16x8 al = Al[(ks * 4 + lg) * 16 + lr];
          #pragma unroll
          for (int st = 0; st < 2; ++st) {
            const size_t bo = (size_t)(st * 16 + lr) * IN0 + ks * 32;
            b16x8 bh = *reinterpret_cast<const b16x8*>(Xh + bo);
            b16x8 bl = *reinterpret_cast<const b16x8*>(Xl + bo);
            acc[st] = mfma16(ah, bh, acc[st]);
            acc[st] = mfma16(ah, bl, acc[st]);
            acc[st] = mfma16(al, bh, acc[st]);
          }
        }
        #pragma unroll 4
        for (int ks = 0; ks < 16; ++ks) {           // h0 part: weight k 64.., in1 cols 0..511
          b16x8 ah = Ah[((8 + ks * 4) + lg) * 16 + lr];
          b16x8 al = Al[((8 + ks * 4) + lg) * 16 + lr];
          #pragma unroll
          for (int st = 0; st < 2; ++st) {
            const size_t bo = (size_t)(st * 16 + lr) * K1 + ks * 32;
            b16x8 bh = *reinterpret_cast<const b16x8*>(Bh + bo);
            b16x8 bl = *reinterpret_cast<const b16x8*>(Bl + bo);
            acc[st] = mfma16(ah, bh, acc[st]);
            acc[st] = mfma16(ah, bl, acc[st]);
            acc[st] = mfma16(al, bh, acc[st]);
          }
        }
      }

      // ---- lane-local cell update; write-through split-bf16 h stores ----
      const int colbase = layer1 ? (512 + hc) : hc;
      #pragma unroll
      for (int st = 0; st < 2; ++st) {
        float i_ = sigm(acc[st][0]);
        float f_ = sigm(acc[st][1]);
        float g_ = tanh_f(acc[st][2]);
        float o_ = sigm(acc[st][3]);
        c[st] = fmaf(f_, c[st], i_ * g_);
        float hv = o_ * tanh_f(c[st]);
        __bf16 hh = (__bf16)hv;
        __bf16 hl = (__bf16)(hv - (float)hh);
        const int b = bbase + st * 16 + lr;
        const size_t idx = ((size_t)pw * BATCH + b) * K1 + colbase;
        store_short_wt(in1hi + idx, (unsigned)__builtin_bit_cast(unsigned short, hh));
        store_short_wt(in1lo + idx, (unsigned)__builtin_bit_cast(unsigned short, hl));
      }
      asm volatile("s_waitcnt vmcnt(0)" ::: "memory");  // release: stores at coherence point
    }
    grid_barrier(bar, (unsigned)(n + 1) * NWG);
  }

  // ---- final FC on h1[511] (written at iter 512, parity 0), cols 512..1023 ----
  if (wg == 0 && tid < BATCH) {
    const __bf16* rh = in1hi + (size_t)tid * K1 + 512;
    const __bf16* rl = in1lo + (size_t)tid * K1 + 512;
    float acc = 0.f;
    #pragma unroll 8
    for (int k = 0; k < HID; ++k)
      acc = fmaf((float)rh[k] + (float)rl[k], fcw[k], acc);
    out[tid] = acc + fcb[0];
  }
}

// ---------- host ----------
extern "C" void kernel_launch(void* const* d_in, const int* in_sizes, int n_in,
                              void* d_out, int out_size, void* d_ws, size_t ws_size,
                              hipStream_t stream) {
  const float* x    = (const float*)d_in[0];
  const float* Wih0 = (const float*)d_in[1];
  const float* Whh0 = (const float*)d_in[2];
  const float* bih0 = (const float*)d_in[3];
  const float* bhh0 = (const float*)d_in[4];
  const float* Wih1 = (const float*)d_in[5];
  const float* Whh1 = (const float*)d_in[6];
  const float* bih1 = (const float*)d_in[7];
  const float* bhh1 = (const float*)d_in[8];
  const float* fcw  = (const float*)d_in[9];
  const float* fcb  = (const float*)d_in[10];

  char* ws = (char*)d_ws;
  size_t off = 0;
  auto alloc = [&](size_t bytes) -> char* {
    char* pp = ws + off;
    off = (off + bytes + 1023) & ~(size_t)1023;
    return pp;
  };
  unsigned* bar  = (unsigned*)alloc(256);
  __bf16* xhi  = (__bf16*)alloc((size_t)T_SEQ * BATCH * IN0 * 2);   // 16.8 MB
  __bf16* xlo  = (__bf16*)alloc((size_t)T_SEQ * BATCH * IN0 * 2);
  __bf16* w0hi = (__bf16*)alloc((size_t)2048 * K0 * 2);             // 2.36 MB
  __bf16* w0lo = (__bf16*)alloc((size_t)2048 * K0 * 2);
  __bf16* w1hi = (__bf16*)alloc((size_t)2048 * K1 * 2);             // 4.2 MB
  __bf16* w1lo = (__bf16*)alloc((size_t)2048 * K1 * 2);
  float*  bias0 = (float*)alloc(2048 * 4);
  float*  bias1 = (float*)alloc(2048 * 4);
  __bf16* in1hi = (__bf16*)alloc((size_t)2 * BATCH * K1 * 2);       // 1 MB
  __bf16* in1lo = (__bf16*)alloc((size_t)2 * BATCH * K1 * 2);

  (void)hipMemsetAsync(bar, 0, 256, stream);
  (void)hipMemsetAsync(in1hi, 0, (size_t)2 * BATCH * K1 * 2, stream);
  (void)hipMemsetAsync(in1lo, 0, (size_t)2 * BATCH * K1 * 2, stream);
  k_split_x<<<(T_SEQ * BATCH * IN0) / 256, 256, 0, stream>>>(x, xhi, xlo);
  k_split_w<<<(int)((2048L * K0 + 255) / 256), 256, 0, stream>>>(Wih0, Whh0, bih0, bhh0, w0hi, w0lo, bias0, IN0);
  k_split_w<<<(int)((2048L * K1 + 255) / 256), 256, 0, stream>>>(Wih1, Whh1, bih1, bhh1, w1hi, w1lo, bias1, HID);
  k_lstm<<<NWG, NTHR, 0, stream>>>(xhi, xlo, w0hi, w0lo, bias0, w1hi, w1lo, bias1,
                                   in1hi, in1lo, fcw, fcb, (float*)d_out, bar);
}

// Round 7
// 17056.113 us; speedup vs baseline: 4.6514x; 1.1351x over previous
//
#include <hip/hip_runtime.h>
#include <math.h>

#define T_SEQ 512
#define BATCH 256
#define HID   512
#define IN0   64
#define K1    1024           /* L1: 512 h0 + 512 h1 */
#define K0    576            /* L0: 64 x + 512 h0   */
#define NWG   256
#define NTHR  512

typedef __bf16 b16x8 __attribute__((ext_vector_type(8)));
typedef float  f32x4 __attribute__((ext_vector_type(4)));

__device__ __forceinline__ float sigm(float x)   { return 1.0f / (1.0f + __expf(-x)); }
__device__ __forceinline__ float tanh_f(float x) { return 2.0f / (1.0f + __expf(-2.0f * x)) - 1.0f; }

__device__ __forceinline__ f32x4 mfma16(b16x8 a, b16x8 b, f32x4 c) {
  return __builtin_amdgcn_mfma_f32_16x16x32_bf16(a, b, c, 0, 0, 0);
}

// write-through store to the coherence point (no dirty L2 anywhere)
__device__ __forceinline__ void store_short_wt(const __bf16* p, unsigned v) {
  asm volatile("global_store_short %0, %1, off sc0 sc1"
               :: "v"((const void*)p), "v"(v) : "memory");
}

// ---------- prep: split W into LDS-order layout ----------
// rows permuted r = hcol*4 + gate; k-concat ih|hh.
// out layout: [slice s=r>>4][kc=k>>3][row16=r&15][ke=k&7]  (16-B chunks contiguous)
__global__ void k_split_w(const float* __restrict__ Wih, const float* __restrict__ Whh,
                          const float* __restrict__ bih, const float* __restrict__ bhh,
                          __bf16* __restrict__ whi, __bf16* __restrict__ wlo,
                          float* __restrict__ bias, int Kin) {
  int K = Kin + HID;
  long idx = (long)blockIdx.x * 256 + threadIdx.x;
  long total = 2048L * K;
  if (idx < total) {
    int k = (int)(idx % K);
    int r = (int)(idx / K);
    int gate = r & 3, hcol = r >> 2;
    int row = gate * HID + hcol;
    float v = (k < Kin) ? Wih[(long)row * Kin + k] : Whh[(long)row * HID + (k - Kin)];
    __bf16 h = (__bf16)v;
    long o = (long)(r >> 4) * 16 * K + (long)(k >> 3) * 128 + (r & 15) * 8 + (k & 7);
    whi[o] = h;
    wlo[o] = (__bf16)(v - (float)h);
  }
  if (idx < 2048) {
    int r = (int)idx;
    int gate = r & 3, hcol = r >> 2;
    int row = gate * HID + hcol;
    bias[r] = bih[row] + bhh[row];
  }
}

// ---------- prep: x[B][T][I] -> split bf16 [T][B][I] ----------
__global__ void k_split_x(const float* __restrict__ x,
                          __bf16* __restrict__ xhi, __bf16* __restrict__ xlo) {
  int idx = blockIdx.x * 256 + threadIdx.x;   // dst index, [t][b][i]
  int i = idx & 63;
  int b = (idx >> 6) & 255;
  int t = idx >> 14;
  float v = x[((size_t)b * T_SEQ + t) * IN0 + i];
  __bf16 h = (__bf16)v;
  xhi[idx] = h;
  xlo[idx] = (__bf16)(v - (float)h);
}

// ---------- two-level tree grid barrier, monotonic counters ----------
// bar[0]            : top counter (one line); barrier e done when top == 8*e
// bar[32 + g*32]    : per-group arrival counter, g = wg&7 (separate 128-B lines)
// All counters monotonic -> no reset/reuse race. Release ordering comes from
// callers' s_waitcnt vmcnt(0) after write-through (sc0 sc1) stores; the
// acquire fence (buffer_inv only) makes peers' WT stores visible.
__device__ __forceinline__ void grid_barrier(unsigned* bar, unsigned epoch) {
  __syncthreads();
  if (threadIdx.x == 0) {
    const unsigned g = blockIdx.x & 7;
    unsigned a = __hip_atomic_fetch_add(&bar[32 + g * 32], 1u,
                                        __ATOMIC_RELAXED, __HIP_MEMORY_SCOPE_AGENT);
    if (a == epoch * 32u - 1u)   // 32nd arrival of this epoch in this group
      __hip_atomic_fetch_add(&bar[0], 1u, __ATOMIC_RELAXED, __HIP_MEMORY_SCOPE_AGENT);
    while ((int)(__hip_atomic_load(&bar[0], __ATOMIC_RELAXED, __HIP_MEMORY_SCOPE_AGENT)
                 - epoch * 8u) < 0)
      __builtin_amdgcn_s_sleep(2);
    __builtin_amdgcn_fence(__ATOMIC_ACQUIRE, "agent");   // buffer_inv only
  }
  __syncthreads();
}

// ---------- persistent MFMA LSTM ----------
// 256 wgs x 512 thr (8 waves, 2/SIMD). wg<128: layer1 rows wg*16..+15;
// wg>=128: layer0 rows (wg-128)*16..+15.
// Wave wv covers batch wv*32..+31 (2 MFMA D-tiles of 16 cols) -> acc[2], c[2].
// Weights (split hi/lo) for the wg's 16 rows live in LDS, loaded ONCE.
// D layout: col=lane&15 (batch), row=(lane>>4)*4+reg. Rows permuted hcol*4+gate =>
// lane's 4 acc regs = i,f,g,o of one (hcol,batch): cell update lane-local, c in regs.
// Activations in1{hi,lo}[2][256][1024]: cols 0..511 = h0, 512..1023 = h1, k-major.
__global__ __launch_bounds__(NTHR, 1) void k_lstm(
    const __bf16* __restrict__ xhi, const __bf16* __restrict__ xlo,
    const __bf16* __restrict__ w0hi, const __bf16* __restrict__ w0lo, const float* __restrict__ bias0,
    const __bf16* __restrict__ w1hi, const __bf16* __restrict__ w1lo, const float* __restrict__ bias1,
    __bf16* __restrict__ in1hi, __bf16* __restrict__ in1lo,
    const float* __restrict__ fcw, const float* __restrict__ fcb,
    float* __restrict__ out, unsigned* __restrict__ bar)
{
  __shared__ __align__(16) __bf16 ldsA[2][16 * K1];   // [hi/lo][kc][row16][8] = 64 KB

  const int tid  = threadIdx.x;
  const int lane = tid & 63;
  const int wv   = __builtin_amdgcn_readfirstlane(tid >> 6);   // 0..7
  const int wg   = blockIdx.x;
  const int layer1 = (wg < 128) ? 1 : 0;
  const int lw   = wg & 127;
  const int bbase = wv * 32;
  const int lr = lane & 15;            // A-row16 / B-batch / D-col offset
  const int lg = lane >> 4;            // k-subgroup (A/B), row-subgroup (D)
  const int KW = layer1 ? K1 : K0;

  // ---- one-time: load this wg's weight slice into LDS (coalesced memcpy) ----
  {
    const b16x8* gh = reinterpret_cast<const b16x8*>((layer1 ? w1hi : w0hi) + (size_t)lw * 16 * KW);
    const b16x8* gl = reinterpret_cast<const b16x8*>((layer1 ? w1lo : w0lo) + (size_t)lw * 16 * KW);
    b16x8* lh = reinterpret_cast<b16x8*>(ldsA[0]);
    b16x8* ll = reinterpret_cast<b16x8*>(ldsA[1]);
    const int nch = 2 * KW;            // 16*KW/8 chunks of 16 B
    for (int ch = tid; ch < nch; ch += NTHR) { lh[ch] = gh[ch]; ll[ch] = gl[ch]; }
  }
  __syncthreads();

  const int hc = lw * 4 + lg;          // hidden column this lane owns
  const float4 b4 = *reinterpret_cast<const float4*>((layer1 ? bias1 : bias0) + hc * 4);
  const b16x8* Ah = reinterpret_cast<const b16x8*>(ldsA[0]);
  const b16x8* Al = reinterpret_cast<const b16x8*>(ldsA[1]);

  float c[2] = {0.f, 0.f};

  #pragma unroll 1
  for (int n = 0; n <= T_SEQ; ++n) {
    const int pr = (n + 1) & 1;   // read parity
    const int pw = n & 1;         // write parity
    const bool active = layer1 ? (n >= 1) : (n < T_SEQ);
    if (active) {
      f32x4 acc[2];
      #pragma unroll
      for (int st = 0; st < 2; ++st) { acc[st][0]=b4.x; acc[st][1]=b4.y; acc[st][2]=b4.z; acc[st][3]=b4.w; }

      const __bf16* Bh = in1hi + ((size_t)pr * BATCH + bbase) * K1 + lg * 8;
      const __bf16* Bl = in1lo + ((size_t)pr * BATCH + bbase) * K1 + lg * 8;

      if (layer1) {
        #pragma unroll 4
        for (int ks = 0; ks < 32; ++ks) {
          b16x8 ah = Ah[(ks * 4 + lg) * 16 + lr];
          b16x8 al = Al[(ks * 4 + lg) * 16 + lr];
          #pragma unroll
          for (int st = 0; st < 2; ++st) {
            const size_t bo = (size_t)(st * 16 + lr) * K1 + ks * 32;
            b16x8 bh = *reinterpret_cast<const b16x8*>(Bh + bo);
            b16x8 bl = *reinterpret_cast<const b16x8*>(Bl + bo);
            acc[st] = mfma16(ah, bh, acc[st]);
            acc[st] = mfma16(ah, bl, acc[st]);
            acc[st] = mfma16(al, bh, acc[st]);
          }
        }
      } else {
        const __bf16* Xh = xhi + ((size_t)n * BATCH + bbase) * IN0 + lg * 8;
        const __bf16* Xl = xlo + ((size_t)n * BATCH + bbase) * IN0 + lg * 8;
        #pragma unroll
        for (int ks = 0; ks < 2; ++ks) {            // x part: k 0..63
          b16x8 ah = Ah[(ks * 4 + lg) * 16 + lr];
          b16x8 al = Al[(ks * 4 + lg) * 16 + lr];
          #pragma unroll
          for (int st = 0; st < 2; ++st) {
            const size_t bo = (size_t)(st * 16 + lr) * IN0 + ks * 32;
            b16x8 bh = *reinterpret_cast<const b16x8*>(Xh + bo);
            b16x8 bl = *reinterpret_cast<const b16x8*>(Xl + bo);
            acc[st] = mfma16(ah, bh, acc[st]);
            acc[st] = mfma16(ah, bl, acc[st]);
            acc[st] = mfma16(al, bh, acc[st]);
          }
        }
        #pragma unroll 4
        for (int ks = 0; ks < 16; ++ks) {           // h0 part: weight k 64.., in1 cols 0..511
          b16x8 ah = Ah[((8 + ks * 4) + lg) * 16 + lr];
          b16x8 al = Al[((8 + ks * 4) + lg) * 16 + lr];
          #pragma unroll
          for (int st = 0; st < 2; ++st) {
            const size_t bo = (size_t)(st * 16 + lr) * K1 + ks * 32;
            b16x8 bh = *reinterpret_cast<const b16x8*>(Bh + bo);
            b16x8 bl = *reinterpret_cast<const b16x8*>(Bl + bo);
            acc[st] = mfma16(ah, bh, acc[st]);
            acc[st] = mfma16(ah, bl, acc[st]);
            acc[st] = mfma16(al, bh, acc[st]);
          }
        }
      }

      // ---- lane-local cell update; write-through split-bf16 h stores ----
      const int colbase = layer1 ? (512 + hc) : hc;
      #pragma unroll
      for (int st = 0; st < 2; ++st) {
        float i_ = sigm(acc[st][0]);
        float f_ = sigm(acc[st][1]);
        float g_ = tanh_f(acc[st][2]);
        float o_ = sigm(acc[st][3]);
        c[st] = fmaf(f_, c[st], i_ * g_);
        float hv = o_ * tanh_f(c[st]);
        __bf16 hh = (__bf16)hv;
        __bf16 hl = (__bf16)(hv - (float)hh);
        const int b = bbase + st * 16 + lr;
        const size_t idx = ((size_t)pw * BATCH + b) * K1 + colbase;
        store_short_wt(in1hi + idx, (unsigned)__builtin_bit_cast(unsigned short, hh));
        store_short_wt(in1lo + idx, (unsigned)__builtin_bit_cast(unsigned short, hl));
      }
      asm volatile("s_waitcnt vmcnt(0)" ::: "memory");  // release: stores at coherence point
    }
    grid_barrier(bar, (unsigned)(n + 1));
  }

  // ---- final FC on h1[511] (written at iter 512, parity 0), cols 512..1023 ----
  if (wg == 0 && tid < BATCH) {
    const __bf16* rh = in1hi + (size_t)tid * K1 + 512;
    const __bf16* rl = in1lo + (size_t)tid * K1 + 512;
    float acc = 0.f;
    #pragma unroll 8
    for (int k = 0; k < HID; ++k)
      acc = fmaf((float)rh[k] + (float)rl[k], fcw[k], acc);
    out[tid] = acc + fcb[0];
  }
}

// ---------- host ----------
extern "C" void kernel_launch(void* const* d_in, const int* in_sizes, int n_in,
                              void* d_out, int out_size, void* d_ws, size_t ws_size,
                              hipStream_t stream) {
  const float* x    = (const float*)d_in[0];
  const float* Wih0 = (const float*)d_in[1];
  const float* Whh0 = (const float*)d_in[2];
  const float* bih0 = (const float*)d_in[3];
  const float* bhh0 = (const float*)d_in[4];
  const float* Wih1 = (const float*)d_in[5];
  const float* Whh1 = (const float*)d_in[6];
  const float* bih1 = (const float*)d_in[7];
  const float* bhh1 = (const float*)d_in[8];
  const float* fcw  = (const float*)d_in[9];
  const float* fcb  = (const float*)d_in[10];

  char* ws = (char*)d_ws;
  size_t off = 0;
  auto alloc = [&](size_t bytes) -> char* {
    char* pp = ws + off;
    off = (off + bytes + 1023) & ~(size_t)1023;
    return pp;
  };
  unsigned* bar  = (unsigned*)alloc(2048);
  __bf16* xhi  = (__bf16*)alloc((size_t)T_SEQ * BATCH * IN0 * 2);   // 16.8 MB
  __bf16* xlo  = (__bf16*)alloc((size_t)T_SEQ * BATCH * IN0 * 2);
  __bf16* w0hi = (__bf16*)alloc((size_t)2048 * K0 * 2);             // 2.36 MB
  __bf16* w0lo = (__bf16*)alloc((size_t)2048 * K0 * 2);
  __bf16* w1hi = (__bf16*)alloc((size_t)2048 * K1 * 2);             // 4.2 MB
  __bf16* w1lo = (__bf16*)alloc((size_t)2048 * K1 * 2);
  float*  bias0 = (float*)alloc(2048 * 4);
  float*  bias1 = (float*)alloc(2048 * 4);
  __bf16* in1hi = (__bf16*)alloc((size_t)2 * BATCH * K1 * 2);       // 1 MB
  __bf16* in1lo = (__bf16*)alloc((size_t)2 * BATCH * K1 * 2);

  (void)hipMemsetAsync(bar, 0, 2048, stream);
  (void)hipMemsetAsync(in1hi, 0, (size_t)2 * BATCH * K1 * 2, stream);
  (void)hipMemsetAsync(in1lo, 0, (size_t)2 * BATCH * K1 * 2, stream);
  k_split_x<<<(T_SEQ * BATCH * IN0) / 256, 256, 0, stream>>>(x, xhi, xlo);
  k_split_w<<<(int)((2048L * K0 + 255) / 256), 256, 0, stream>>>(Wih0, Whh0, bih0, bhh0, w0hi, w0lo, bias0, IN0);
  k_split_w<<<(int)((2048L * K1 + 255) / 256), 256, 0, stream>>>(Wih1, Whh1, bih1, bhh1, w1hi, w1lo, bias1, HID);
  k_lstm<<<NWG, NTHR, 0, stream>>>(xhi, xlo, w0hi, w0lo, bias0, w1hi, w1lo, bias1,
                                   in1hi, in1lo, fcw, fcb, (float*)d_out, bar);
}